// Round 11
// baseline (97.469 us; speedup 1.0000x reference)
//
#include <hip/hip_runtime.h>
#include <hip/hip_bf16.h>
#include <stdint.h>
#include <math.h>

#define NROWS 8192
#define DIM   256
#define RB    256          // row bytes (fp8)
#define BI    128          // i rows per tile block
#define JSUB  64           // j rows per sub-tile (LDS double-buffered)
#define NBJS  8
#define JBLK  (JSUB*NBJS)  // 512 j rows per tile block
#define NG    (NROWS/JBLK) // 16
#define NIT   (NROWS/BI)   // 64
#define NCLS  64
#define CAP   256          // max class members (mean 128, sd ~11)

typedef __attribute__((ext_vector_type(4)))  int   int4v;
typedef __attribute__((ext_vector_type(8)))  int   int8v;
typedef __attribute__((ext_vector_type(16))) float floatx16;

typedef const __attribute__((address_space(1))) uint32_t gas_u32;
typedef __attribute__((address_space(3))) uint32_t las_u32;

#define SCALE_1_16 0x7B7B7B7B          // E8M0 123 = 2^-4 in every byte
#define L2E10      14.4269504088896f   // 10 * log2(e)
#define CA_SCALE   (L2E10 * 16.0f)     // A-side fp8 pre-scale -> acc = L2E10*cos
#define CB_SCALE   16.0f               // B-side fp8 pre-scale

#if __has_builtin(__builtin_amdgcn_exp2f)
#define EXP2(x) __builtin_amdgcn_exp2f(x)   // raw v_exp_f32; inputs <= 14.43, safe
#else
#define EXP2(x) exp2f(x)
#endif

__device__ __forceinline__ void gload_lds16(const void* g, void* l) {
    // LDS dest = wave-uniform base + lane*16 ; global src per-lane
    __builtin_amdgcn_global_load_lds((gas_u32*)(uintptr_t)g,
                                     (las_u32*)(uintptr_t)l, 16, 0, 0);
}

// ---- Kernel 1: row-normalize fp32 -> two fp8 e4m3 arrays (A: x230.83, B: x16) ----
// acc = (CA*e_j)*(CB*e_i)*2^-8 = L2E10*cos  -> epilogue is exp2+add only.
__global__ __launch_bounds__(256) void normalize_kernel(const float* __restrict__ emb,
                                                        uint32_t* __restrict__ a8,
                                                        uint32_t* __restrict__ b8,
                                                        float* __restrict__ out)
{
    if (blockIdx.x == 0 && threadIdx.x == 0) *out = 0.f;   // replaces memset dispatch
    int row  = blockIdx.x * 4 + (threadIdx.x >> 6);
    int lane = threadIdx.x & 63;
    float4 v = ((const float4*)(emb + (size_t)row * DIM))[lane];
    float ss = v.x*v.x + v.y*v.y + v.z*v.z + v.w*v.w;
    #pragma unroll
    for (int off = 32; off > 0; off >>= 1)
        ss += __shfl_xor(ss, off, 64);
    float inv = 1.0f / fmaxf(sqrtf(ss), 1e-8f);
    float ia = CA_SCALE * inv, ib = CB_SCALE * inv;
    int ra = __builtin_amdgcn_cvt_pk_fp8_f32(v.x * ia, v.y * ia, 0, false);
    ra     = __builtin_amdgcn_cvt_pk_fp8_f32(v.z * ia, v.w * ia, ra, true);
    int rb = __builtin_amdgcn_cvt_pk_fp8_f32(v.x * ib, v.y * ib, 0, false);
    rb     = __builtin_amdgcn_cvt_pk_fp8_f32(v.z * ib, v.w * ib, rb, true);
    a8[(size_t)row * 64 + lane] = (uint32_t)ra;
    b8[(size_t)row * 64 + lane] = (uint32_t)rb;
}

// ---- Kernel 2 (fused, grid EXACTLY 1024 = 4 blocks/CU): tile path for all blocks;
//      the 64 diagonal blocks (jg == bi>>2) additionally compute class bi's positives. ----
template<bool DIAG>
__device__ __forceinline__ void epi(const floatx16 acc[2],
                                    int jbs, int h, int ic0, float& ts)
{
    #pragma unroll
    for (int jt = 0; jt < 2; ++jt)
        #pragma unroll
        for (int rq = 0; rq < 4; ++rq)
            #pragma unroll
            for (int r2 = 0; r2 < 4; ++r2) {
                float v = EXP2(acc[jt][rq * 4 + r2]);   // acc already = L2E10*cos
                if (DIAG) {
                    const int jg_ = jbs + jt * 32 + rq * 8 + h * 4 + r2;
                    if (jg_ == ic0) v = 0.f;            // exclude diagonal
                }
                ts += v;
            }
}

__global__ __launch_bounds__(256, 4) void fused_kernel(const uint8_t* __restrict__ eA,
                                                       const uint8_t* __restrict__ eB,
                                                       const int* __restrict__ tgt,
                                                       float* __restrict__ pts,
                                                       float* __restrict__ sp)
{
    __shared__ uint8_t smem[2 * JSUB * RB];   // 32 KB: tile A dbuf, then pos idx scratch

    const int bi   = blockIdx.x;
    const int jg   = blockIdx.y;
    const int tid  = threadIdx.x;
    const int wave = tid >> 6;
    const int lane = tid & 63;
    const int col  = lane & 31;
    const int h    = lane >> 5;

    // ================= negatives/total tile path (all 1024 blocks) =================
    // B fragments straight from global to registers, once per block (L2-hit)
    const uint8_t* pbB = eB + (size_t)(bi * BI + wave * 32 + col) * RB + h * 32;
    int8v bfr[4];
    #pragma unroll
    for (int s = 0; s < 4; ++s)
        bfr[s] = *(const int8v*)(pbB + s * 64);

    // A staging map (mod-16 xor swizzle on 16B chunks of 256B rows)
    int goffA[4];
    #pragma unroll
    for (int t = 0; t < 4; ++t) {
        int s   = wave * 256 + t * 64 + lane;
        int row = s >> 4;
        int lc  = (s & 15) ^ (row & 15);
        goffA[t] = row * RB + lc * 16;
    }
    const char* gA = (const char*)(eA + (size_t)jg * JBLK * RB);

    #pragma unroll
    for (int t = 0; t < 4; ++t)
        gload_lds16(gA + goffA[t], smem + wave * 4096 + t * 1024);

    const int ic0 = bi * BI + wave * 32 + col;   // this lane's i

    const int xm = col & 15;
    int poff[4];
    #pragma unroll
    for (int s = 0; s < 4; ++s)
        poff[s] = ((s * 4 + h * 2) ^ xm) << 4;   // partner chunk = poff[s]^16

    __syncthreads();   // drains A0 DMA

    float ts = 0.f;
    const int dpair = bi - jg * 4;   // sub-tile pair touching the diagonal (if 0..3)

    #pragma unroll
    for (int bjs = 0; bjs < NBJS; ++bjs) {
        if (bjs < NBJS - 1) {   // issue next A stage; drains at phase-end barrier
            const char* gAn = gA + (size_t)(bjs + 1) * JSUB * RB;
            #pragma unroll
            for (int t = 0; t < 4; ++t)
                gload_lds16(gAn + goffA[t],
                            smem + ((bjs + 1) & 1) * (JSUB * RB) + wave * 4096 + t * 1024);
        }

        const uint8_t* ab = smem + (bjs & 1) * (JSUB * RB);
        floatx16 acc[2];
        #pragma unroll
        for (int jt = 0; jt < 2; ++jt)
            acc[jt] = (floatx16){0.f,0.f,0.f,0.f,0.f,0.f,0.f,0.f,
                                 0.f,0.f,0.f,0.f,0.f,0.f,0.f,0.f};

        #pragma unroll
        for (int s = 0; s < 4; ++s) {
            int8v af[2];
            #pragma unroll
            for (int jt = 0; jt < 2; ++jt) {
                const uint8_t* pa = ab + (size_t)(jt * 32 + col) * RB;
                int4v lo = *(const int4v*)(pa + poff[s]);
                int4v hi = *(const int4v*)(pa + (poff[s] ^ 16));
                af[jt] = __builtin_shufflevector(lo, hi, 0, 1, 2, 3, 4, 5, 6, 7);
            }
            #pragma unroll
            for (int jt = 0; jt < 2; ++jt)
                acc[jt] = __builtin_amdgcn_mfma_scale_f32_32x32x64_f8f6f4(
                    af[jt], bfr[s], acc[jt], 0, 0,
                    0, SCALE_1_16, 0, SCALE_1_16);
        }

        const int jbs = jg * JBLK + bjs * JSUB;
        if ((bjs >> 1) == dpair)
            epi<true >(acc, jbs, h, ic0, ts);
        else
            epi<false>(acc, jbs, h, ic0, ts);

        if (bjs < NBJS - 1)
            __syncthreads();   // drains next-A DMA; guards restage of buffer just read
    }

    ts += __shfl_xor(ts, 32, 64);   // L and L+32: same i, disjoint j-halves
    if (h == 0)
        pts[(size_t)jg * NROWS + ic0] = ts;

    // ================= positives tail: only the 64 diagonal blocks =================
    if (jg != (bi >> 2)) return;
    const int c = bi;   // this block's class

    __syncthreads();    // all waves done with smem (tile dbuf) -> repurpose
    int* idx = (int*)smem;
    int* cnt = (int*)(smem + CAP * 4);
    if (tid == 0) *cnt = 0;
    __syncthreads();
    // scan all targets (coalesced int4 loads, batched)
    int4v tv[8];
    #pragma unroll
    for (int k = 0; k < 8; ++k)
        tv[k] = *(const int4v*)(tgt + k * 1024 + tid * 4);
    #pragma unroll
    for (int k = 0; k < 8; ++k)
        #pragma unroll
        for (int r = 0; r < 4; ++r)
            if (tv[k][r] == c) {
                int p = atomicAdd(cnt, 1);
                if (p < CAP) idx[p] = k * 1024 + tid * 4 + r;
            }
    __syncthreads();
    const int M   = min(*cnt, CAP);
    const int Mp  = (M + 31) & ~31;
    const int nbt = Mp >> 5;

    // fragments straight from L2 (f8f6f4 layout: lane row, k [s*64+h*32,+32))
    for (int bt = wave; bt < nbt; bt += 4) {
        const int b = bt * 32 + col;
        const uint8_t* pb = eB + (size_t)idx[min(b, M - 1)] * RB + h * 32;
        int8v bpr[4];
        #pragma unroll
        for (int s = 0; s < 4; ++s)
            bpr[s] = *(const int8v*)(pb + s * 64);
        float psum = 0.f;
        for (int at = 0; at < nbt; ++at) {
            const uint8_t* pa = eA + (size_t)idx[min(at * 32 + col, M - 1)] * RB + h * 32;
            floatx16 acc = (floatx16){0.f,0.f,0.f,0.f,0.f,0.f,0.f,0.f,
                                      0.f,0.f,0.f,0.f,0.f,0.f,0.f,0.f};
            #pragma unroll
            for (int s = 0; s < 4; ++s) {
                int8v af = *(const int8v*)(pa + s * 64);
                acc = __builtin_amdgcn_mfma_scale_f32_32x32x64_f8f6f4(
                    af, bpr[s], acc, 0, 0, 0, SCALE_1_16, 0, SCALE_1_16);
            }
            #pragma unroll
            for (int rq = 0; rq < 4; ++rq)
                #pragma unroll
                for (int r2 = 0; r2 < 4; ++r2) {
                    const int a = at * 32 + rq * 8 + h * 4 + r2;
                    float v = EXP2(acc[rq * 4 + r2]);
                    psum += (a != b && a < M) ? v : 0.f;   // exact diag/pad mask
                }
        }
        psum += __shfl_xor(psum, 32, 64);   // h-halves: disjoint a's, same b
        if (h == 0 && b < M) sp[idx[b]] = psum;
    }
}

// ---- Kernel 3: per-row log-diff + global sum ----
__global__ __launch_bounds__(256) void finalize_kernel(const float* __restrict__ pts,
                                                       const float* __restrict__ sp,
                                                       float* __restrict__ out)
{
    const int i = blockIdx.x * 256 + threadIdx.x;
    float st = 0.f;
    #pragma unroll
    for (int t = 0; t < NG; ++t)
        st += pts[(size_t)t * NROWS + i];
    const float spv = sp[i];
    const float ns  = st - spv;          // negatives = total - positives (diag-free both)
    float loss = logf(ns) - logf(spv);
    #pragma unroll
    for (int off = 32; off > 0; off >>= 1)
        loss += __shfl_xor(loss, off, 64);
    __shared__ float w4[4];
    if ((threadIdx.x & 63) == 0) w4[threadIdx.x >> 6] = loss;
    __syncthreads();
    if (threadIdx.x == 0)
        atomicAdd(out, w4[0] + w4[1] + w4[2] + w4[3]);
}

extern "C" void kernel_launch(void* const* d_in, const int* in_sizes, int n_in,
                              void* d_out, int out_size, void* d_ws, size_t ws_size,
                              hipStream_t stream)
{
    (void)in_sizes; (void)n_in; (void)out_size; (void)ws_size;
    const float* emb = (const float*)d_in[0];
    const int*   tgt = (const int*)d_in[1];
    float*       out = (float*)d_out;

    uint32_t* a8  = (uint32_t*)d_ws;                                  // 2 MB
    uint32_t* b8  = a8 + (size_t)NROWS * 64;                          // 2 MB
    float*    pts = (float*)(b8 + (size_t)NROWS * 64);                // 512 KB
    float*    sp  = pts + (size_t)NG * NROWS;                         // 32 KB

    normalize_kernel<<<NROWS / 4, 256, 0, stream>>>(emb, a8, b8, out);

    dim3 grid(NIT, NG);   // exactly 1024 blocks = 4 per CU, no second round
    fused_kernel<<<grid, 256, 0, stream>>>(
        (const uint8_t*)a8, (const uint8_t*)b8, tgt, pts, sp);

    finalize_kernel<<<NROWS / 256, 256, 0, stream>>>(pts, sp, out);
}

// Round 13
// 89.497 us; speedup vs baseline: 1.0891x; 1.0891x over previous
//
#include <hip/hip_runtime.h>
#include <hip/hip_bf16.h>
#include <stdint.h>
#include <math.h>

#define NROWS 8192
#define DIM   256
#define RB    256          // row bytes (fp8)
#define BI    128          // i rows per tile block
#define JSUB  64           // j rows per sub-tile (LDS double-buffered)
#define NBJS  8
#define JBLK  (JSUB*NBJS)  // 512 j rows per tile block
#define NG    (NROWS/JBLK) // 16
#define NIT   (NROWS/BI)   // 64
#define NCLS  64
#define CAP   256          // max class members (mean 128, sd ~11; fixed seed)

typedef __attribute__((ext_vector_type(4)))  int   int4v;
typedef __attribute__((ext_vector_type(8)))  int   int8v;
typedef __attribute__((ext_vector_type(16))) float floatx16;

typedef const __attribute__((address_space(1))) uint32_t gas_u32;
typedef __attribute__((address_space(3))) uint32_t las_u32;

#define SCALE_1_16 0x7B7B7B7B          // E8M0 123 = 2^-4 in every byte
#define L2E10      14.4269504088896f   // 10 * log2(e)
#define CA_SCALE   (L2E10 * 16.0f)     // A-side fp8 pre-scale -> acc = L2E10*cos
#define CB_SCALE   16.0f               // B-side fp8 pre-scale

#if __has_builtin(__builtin_amdgcn_exp2f)
#define EXP2(x) __builtin_amdgcn_exp2f(x)   // raw v_exp_f32; inputs <= 14.43, safe
#else
#define EXP2(x) exp2f(x)
#endif

__device__ __forceinline__ void gload_lds16(const void* g, void* l) {
    // LDS dest = wave-uniform base + lane*16 ; global src per-lane
    __builtin_amdgcn_global_load_lds((gas_u32*)(uintptr_t)g,
                                     (las_u32*)(uintptr_t)l, 16, 0, 0);
}

// ---- Kernel 1: row-normalize fp32 -> two fp8 e4m3 arrays (A: x230.83, B: x16) ----
// acc = (CA*e_j)*(CB*e_i)*2^-8 = L2E10*cos  -> epilogue is exp2+add only.
__global__ __launch_bounds__(256) void normalize_kernel(const float* __restrict__ emb,
                                                        uint32_t* __restrict__ a8,
                                                        uint32_t* __restrict__ b8,
                                                        float* __restrict__ out)
{
    if (blockIdx.x == 0 && threadIdx.x == 0) *out = 0.f;   // replaces memset dispatch
    int row  = blockIdx.x * 4 + (threadIdx.x >> 6);
    int lane = threadIdx.x & 63;
    float4 v = ((const float4*)(emb + (size_t)row * DIM))[lane];
    float ss = v.x*v.x + v.y*v.y + v.z*v.z + v.w*v.w;
    #pragma unroll
    for (int off = 32; off > 0; off >>= 1)
        ss += __shfl_xor(ss, off, 64);
    float inv = 1.0f / fmaxf(sqrtf(ss), 1e-8f);
    float ia = CA_SCALE * inv, ib = CB_SCALE * inv;
    int ra = __builtin_amdgcn_cvt_pk_fp8_f32(v.x * ia, v.y * ia, 0, false);
    ra     = __builtin_amdgcn_cvt_pk_fp8_f32(v.z * ia, v.w * ia, ra, true);
    int rb = __builtin_amdgcn_cvt_pk_fp8_f32(v.x * ib, v.y * ib, 0, false);
    rb     = __builtin_amdgcn_cvt_pk_fp8_f32(v.z * ib, v.w * ib, rb, true);
    a8[(size_t)row * 64 + lane] = (uint32_t)ra;
    b8[(size_t)row * 64 + lane] = (uint32_t)rb;
}

// ---- Kernel 2: per-class member lists (global) + zero sp ----
__global__ __launch_bounds__(256) void bucket_kernel(const int* __restrict__ tgt,
                                                     int* __restrict__ cidx,
                                                     int* __restrict__ ccnt,
                                                     float* __restrict__ sp)
{
    __shared__ int cnt;
    const int c = blockIdx.x, tid = threadIdx.x;
    if (tid == 0) cnt = 0;
    if (tid < 128) sp[c * 128 + tid] = 0.f;   // zero sp (atomics accumulate into it)
    __syncthreads();
    #pragma unroll
    for (int k = 0; k < 8; ++k) {
        int4v tv = *(const int4v*)(tgt + k * 1024 + tid * 4);
        #pragma unroll
        for (int r = 0; r < 4; ++r)
            if (tv[r] == c) {
                int p = atomicAdd(&cnt, 1);
                if (p < CAP) cidx[c * CAP + p] = k * 1024 + tid * 4 + r;
            }
    }
    __syncthreads();
    if (tid == 0) ccnt[c] = min(cnt, CAP);
}

// ---- Kernel 3 (fused, grid EXACTLY 64x16 = 1024 = 4/CU): tile path for all blocks;
//      pos sliced into 64 wave-slots per class: w64 = jg*4+wave -> (bt, at) 8x8. ----
template<bool DIAG>
__device__ __forceinline__ void epi(const floatx16 acc[2],
                                    int jbs, int h, int ic0, float& ts)
{
    #pragma unroll
    for (int jt = 0; jt < 2; ++jt)
        #pragma unroll
        for (int rq = 0; rq < 4; ++rq)
            #pragma unroll
            for (int r2 = 0; r2 < 4; ++r2) {
                float v = EXP2(acc[jt][rq * 4 + r2]);   // acc already = L2E10*cos
                if (DIAG) {
                    const int jg_ = jbs + jt * 32 + rq * 8 + h * 4 + r2;
                    if (jg_ == ic0) v = 0.f;            // exclude diagonal
                }
                ts += v;
            }
}

__global__ __launch_bounds__(256, 4) void fused_kernel(const uint8_t* __restrict__ eA,
                                                       const uint8_t* __restrict__ eB,
                                                       const int* __restrict__ cidx,
                                                       const int* __restrict__ ccnt,
                                                       float* __restrict__ pts,
                                                       float* __restrict__ sp)
{
    __shared__ uint8_t smem[2 * JSUB * RB];   // 32 KB tile A double-buffer

    const int bi   = blockIdx.x;
    const int jg   = blockIdx.y;
    const int tid  = threadIdx.x;
    const int wave = tid >> 6;
    const int lane = tid & 63;
    const int col  = lane & 31;
    const int h    = lane >> 5;

    // ================= negatives/total tile path (all 1024 blocks) =================
    const uint8_t* pbB = eB + (size_t)(bi * BI + wave * 32 + col) * RB + h * 32;
    int8v bfr[4];
    #pragma unroll
    for (int s = 0; s < 4; ++s)
        bfr[s] = *(const int8v*)(pbB + s * 64);

    int goffA[4];
    #pragma unroll
    for (int t = 0; t < 4; ++t) {
        int s   = wave * 256 + t * 64 + lane;
        int row = s >> 4;
        int lc  = (s & 15) ^ (row & 15);
        goffA[t] = row * RB + lc * 16;
    }
    const char* gA = (const char*)(eA + (size_t)jg * JBLK * RB);

    #pragma unroll
    for (int t = 0; t < 4; ++t)
        gload_lds16(gA + goffA[t], smem + wave * 4096 + t * 1024);

    const int ic0 = bi * BI + wave * 32 + col;   // this lane's i

    const int xm = col & 15;
    int poff[4];
    #pragma unroll
    for (int s = 0; s < 4; ++s)
        poff[s] = ((s * 4 + h * 2) ^ xm) << 4;   // partner chunk = poff[s]^16

    __syncthreads();   // drains A0 DMA

    float ts = 0.f;
    const int dpair = bi - jg * 4;   // sub-tile pair touching the diagonal (if 0..3)

    #pragma unroll
    for (int bjs = 0; bjs < NBJS; ++bjs) {
        if (bjs < NBJS - 1) {   // issue next A stage; drains at phase-end barrier
            const char* gAn = gA + (size_t)(bjs + 1) * JSUB * RB;
            #pragma unroll
            for (int t = 0; t < 4; ++t)
                gload_lds16(gAn + goffA[t],
                            smem + ((bjs + 1) & 1) * (JSUB * RB) + wave * 4096 + t * 1024);
        }

        const uint8_t* ab = smem + (bjs & 1) * (JSUB * RB);
        floatx16 acc[2];
        #pragma unroll
        for (int jt = 0; jt < 2; ++jt)
            acc[jt] = (floatx16){0.f,0.f,0.f,0.f,0.f,0.f,0.f,0.f,
                                 0.f,0.f,0.f,0.f,0.f,0.f,0.f,0.f};

        #pragma unroll
        for (int s = 0; s < 4; ++s) {
            int8v af[2];
            #pragma unroll
            for (int jt = 0; jt < 2; ++jt) {
                const uint8_t* pa = ab + (size_t)(jt * 32 + col) * RB;
                int4v lo = *(const int4v*)(pa + poff[s]);
                int4v hi = *(const int4v*)(pa + (poff[s] ^ 16));
                af[jt] = __builtin_shufflevector(lo, hi, 0, 1, 2, 3, 4, 5, 6, 7);
            }
            #pragma unroll
            for (int jt = 0; jt < 2; ++jt)
                acc[jt] = __builtin_amdgcn_mfma_scale_f32_32x32x64_f8f6f4(
                    af[jt], bfr[s], acc[jt], 0, 0,
                    0, SCALE_1_16, 0, SCALE_1_16);
        }

        const int jbs = jg * JBLK + bjs * JSUB;
        if ((bjs >> 1) == dpair)
            epi<true >(acc, jbs, h, ic0, ts);
        else
            epi<false>(acc, jbs, h, ic0, ts);

        if (bjs < NBJS - 1)
            __syncthreads();   // drains next-A DMA; guards restage of buffer just read
    }

    ts += __shfl_xor(ts, 32, 64);   // L and L+32: same i, disjoint j-halves
    if (h == 0)
        pts[(size_t)jg * NROWS + ic0] = ts;

    // ===== positives tail: 64 wave-slots per class (no LDS, no barriers) =====
    // wave-slot w64 -> one 32x32 Gram tile (b-tile bt, a-tile at) of class bi.
    const int c   = bi;
    const int M   = ccnt[c];
    const int nbt = (M + 31) >> 5;
    const int w64 = jg * 4 + wave;
    const int bt  = w64 >> 3;
    const int at  = w64 & 7;
    if (bt >= nbt || at >= nbt) return;   // wave-divergent exit is safe: no barriers below

    const int* idx = cidx + c * CAP;
    const int b    = bt * 32 + col;
    const int bidx = idx[min(b, M - 1)];

    const uint8_t* pb2 = eB + (size_t)bidx * RB + h * 32;
    int8v bpr[4];
    #pragma unroll
    for (int s = 0; s < 4; ++s)
        bpr[s] = *(const int8v*)(pb2 + s * 64);

    // A fragments per lane straight from L2 (R10-verified pattern)
    const uint8_t* pa2 = eA + (size_t)idx[min(at * 32 + col, M - 1)] * RB + h * 32;
    floatx16 acc2 = (floatx16){0.f,0.f,0.f,0.f,0.f,0.f,0.f,0.f,
                               0.f,0.f,0.f,0.f,0.f,0.f,0.f,0.f};
    #pragma unroll
    for (int s = 0; s < 4; ++s) {
        int8v af = *(const int8v*)(pa2 + s * 64);
        acc2 = __builtin_amdgcn_mfma_scale_f32_32x32x64_f8f6f4(
            af, bpr[s], acc2, 0, 0, 0, SCALE_1_16, 0, SCALE_1_16);
    }

    float psum = 0.f;
    #pragma unroll
    for (int rq = 0; rq < 4; ++rq)
        #pragma unroll
        for (int r2 = 0; r2 < 4; ++r2) {
            const int a = at * 32 + rq * 8 + h * 4 + r2;
            float v = EXP2(acc2[rq * 4 + r2]);
            psum += (a != b && a < M) ? v : 0.f;   // exact diag/pad mask
        }
    psum += __shfl_xor(psum, 32, 64);   // h-halves: disjoint a's, same b
    if (h == 0 && b < M)
        atomicAdd(&sp[bidx], psum);     // nbt contributors per row (one per a-tile)
}

// ---- Kernel 4: per-row log-diff + global sum ----
__global__ __launch_bounds__(256) void finalize_kernel(const float* __restrict__ pts,
                                                       const float* __restrict__ sp,
                                                       float* __restrict__ out)
{
    const int i = blockIdx.x * 256 + threadIdx.x;
    float st = 0.f;
    #pragma unroll
    for (int t = 0; t < NG; ++t)
        st += pts[(size_t)t * NROWS + i];
    const float spv = sp[i];
    const float ns  = st - spv;          // negatives = total - positives (diag-free both)
    float loss = logf(ns) - logf(spv);
    #pragma unroll
    for (int off = 32; off > 0; off >>= 1)
        loss += __shfl_xor(loss, off, 64);
    __shared__ float w4[4];
    if ((threadIdx.x & 63) == 0) w4[threadIdx.x >> 6] = loss;
    __syncthreads();
    if (threadIdx.x == 0)
        atomicAdd(out, w4[0] + w4[1] + w4[2] + w4[3]);
}

extern "C" void kernel_launch(void* const* d_in, const int* in_sizes, int n_in,
                              void* d_out, int out_size, void* d_ws, size_t ws_size,
                              hipStream_t stream)
{
    (void)in_sizes; (void)n_in; (void)out_size; (void)ws_size;
    const float* emb = (const float*)d_in[0];
    const int*   tgt = (const int*)d_in[1];
    float*       out = (float*)d_out;

    uint32_t* a8   = (uint32_t*)d_ws;                                 // 2 MB
    uint32_t* b8   = a8 + (size_t)NROWS * 64;                         // 2 MB
    float*    pts  = (float*)(b8 + (size_t)NROWS * 64);               // 512 KB
    float*    sp   = pts + (size_t)NG * NROWS;                        // 32 KB
    int*      cidx = (int*)(sp + NROWS);                              // 64 KB
    int*      ccnt = cidx + NCLS * CAP;                               // 256 B

    normalize_kernel<<<NROWS / 4, 256, 0, stream>>>(emb, a8, b8, out);

    bucket_kernel<<<NCLS, 256, 0, stream>>>(tgt, cidx, ccnt, sp);

    dim3 grid(NIT, NG);   // exactly 1024 blocks = 4 per CU, no second round
    fused_kernel<<<grid, 256, 0, stream>>>(
        (const uint8_t*)a8, (const uint8_t*)b8, cidx, ccnt, pts, sp);

    finalize_kernel<<<NROWS / 256, 256, 0, stream>>>(pts, sp, out);
}

// Round 14
// 88.134 us; speedup vs baseline: 1.1059x; 1.0155x over previous
//
#include <hip/hip_runtime.h>
#include <hip/hip_bf16.h>
#include <stdint.h>
#include <math.h>

#define NROWS 8192
#define DIM   256
#define RB    256          // row bytes (fp8)
#define BI    128          // i rows per tile block
#define JSUB  64           // j rows per sub-tile (LDS double-buffered)
#define NBJS  8
#define JBLK  (JSUB*NBJS)  // 512 j rows per tile block
#define NG    (NROWS/JBLK) // 16
#define NIT   (NROWS/BI)   // 64
#define NCLS  64
#define CAP   256          // max class members (mean 128, sd ~11; fixed seed)

typedef __attribute__((ext_vector_type(4)))  int   int4v;
typedef __attribute__((ext_vector_type(8)))  int   int8v;
typedef __attribute__((ext_vector_type(16))) float floatx16;

typedef const __attribute__((address_space(1))) uint32_t gas_u32;
typedef __attribute__((address_space(3))) uint32_t las_u32;

#define SCALE_1_16 0x7B7B7B7B          // E8M0 123 = 2^-4 in every byte
#define L2E10      14.4269504088896f   // 10 * log2(e)
#define CA_SCALE   (L2E10 * 16.0f)     // A-side fp8 pre-scale -> acc = L2E10*cos
#define CB_SCALE   16.0f               // B-side fp8 pre-scale

#if __has_builtin(__builtin_amdgcn_exp2f)
#define EXP2(x) __builtin_amdgcn_exp2f(x)   // raw v_exp_f32; inputs <= 14.43, safe
#else
#define EXP2(x) exp2f(x)
#endif

__device__ __forceinline__ void gload_lds16(const void* g, void* l) {
    // LDS dest = wave-uniform base + lane*16 ; global src per-lane
    __builtin_amdgcn_global_load_lds((gas_u32*)(uintptr_t)g,
                                     (las_u32*)(uintptr_t)l, 16, 0, 0);
}

// ---- Kernel 1 (merged): blocks <2048 row-normalize fp32 -> two fp8 arrays;
//      blocks >=2048 build per-class member lists + zero sp (former bucket_kernel). ----
__global__ __launch_bounds__(256) void normalize_kernel(const float* __restrict__ emb,
                                                        const int* __restrict__ tgt,
                                                        uint32_t* __restrict__ a8,
                                                        uint32_t* __restrict__ b8,
                                                        int* __restrict__ cidx,
                                                        int* __restrict__ ccnt,
                                                        float* __restrict__ sp,
                                                        float* __restrict__ out)
{
    const int tid = threadIdx.x;
    if (blockIdx.x >= NROWS / 4) {
        // ---- bucket path (64 blocks): class c member list + zero sp ----
        __shared__ int cnt;
        const int c = blockIdx.x - NROWS / 4;
        if (tid == 0) cnt = 0;
        if (tid < 128) sp[c * 128 + tid] = 0.f;   // zero sp (atomics accumulate)
        __syncthreads();
        #pragma unroll
        for (int k = 0; k < 8; ++k) {
            int4v tv = *(const int4v*)(tgt + k * 1024 + tid * 4);
            #pragma unroll
            for (int r = 0; r < 4; ++r)
                if (tv[r] == c) {
                    int p = atomicAdd(&cnt, 1);
                    if (p < CAP) cidx[c * CAP + p] = k * 1024 + tid * 4 + r;
                }
        }
        __syncthreads();
        if (tid == 0) ccnt[c] = min(cnt, CAP);
        return;
    }
    // ---- normalize path: acc = (CA*e_j)*(CB*e_i)*2^-8 = L2E10*cos ----
    if (blockIdx.x == 0 && tid == 0) *out = 0.f;   // replaces memset dispatch
    int row  = blockIdx.x * 4 + (tid >> 6);
    int lane = tid & 63;
    float4 v = ((const float4*)(emb + (size_t)row * DIM))[lane];
    float ss = v.x*v.x + v.y*v.y + v.z*v.z + v.w*v.w;
    #pragma unroll
    for (int off = 32; off > 0; off >>= 1)
        ss += __shfl_xor(ss, off, 64);
    float inv = 1.0f / fmaxf(sqrtf(ss), 1e-8f);
    float ia = CA_SCALE * inv, ib = CB_SCALE * inv;
    int ra = __builtin_amdgcn_cvt_pk_fp8_f32(v.x * ia, v.y * ia, 0, false);
    ra     = __builtin_amdgcn_cvt_pk_fp8_f32(v.z * ia, v.w * ia, ra, true);
    int rb = __builtin_amdgcn_cvt_pk_fp8_f32(v.x * ib, v.y * ib, 0, false);
    rb     = __builtin_amdgcn_cvt_pk_fp8_f32(v.z * ib, v.w * ib, rb, true);
    a8[(size_t)row * 64 + lane] = (uint32_t)ra;
    b8[(size_t)row * 64 + lane] = (uint32_t)rb;
}

// ---- Kernel 2 (fused, grid EXACTLY 64x16 = 1024 = 4/CU): tile path for all blocks;
//      pos sliced into 64 wave-slots per class: w64 = jg*4+wave -> (bt, at) 8x8. ----
template<bool DIAG>
__device__ __forceinline__ void epi(const floatx16 acc[2],
                                    int jbs, int h, int ic0, float& ts)
{
    #pragma unroll
    for (int jt = 0; jt < 2; ++jt)
        #pragma unroll
        for (int rq = 0; rq < 4; ++rq)
            #pragma unroll
            for (int r2 = 0; r2 < 4; ++r2) {
                float v = EXP2(acc[jt][rq * 4 + r2]);   // acc already = L2E10*cos
                if (DIAG) {
                    const int jg_ = jbs + jt * 32 + rq * 8 + h * 4 + r2;
                    if (jg_ == ic0) v = 0.f;            // exclude diagonal
                }
                ts += v;
            }
}

__global__ __launch_bounds__(256, 4) void fused_kernel(const uint8_t* __restrict__ eA,
                                                       const uint8_t* __restrict__ eB,
                                                       const int* __restrict__ cidx,
                                                       const int* __restrict__ ccnt,
                                                       float* __restrict__ pts,
                                                       float* __restrict__ sp)
{
    __shared__ uint8_t smem[2 * JSUB * RB];   // 32 KB tile A double-buffer

    const int bi   = blockIdx.x;
    const int jg   = blockIdx.y;
    const int tid  = threadIdx.x;
    const int wave = tid >> 6;
    const int lane = tid & 63;
    const int col  = lane & 31;
    const int h    = lane >> 5;

    // ================= negatives/total tile path (all 1024 blocks) =================
    const uint8_t* pbB = eB + (size_t)(bi * BI + wave * 32 + col) * RB + h * 32;
    int8v bfr[4];
    #pragma unroll
    for (int s = 0; s < 4; ++s)
        bfr[s] = *(const int8v*)(pbB + s * 64);

    int goffA[4];
    #pragma unroll
    for (int t = 0; t < 4; ++t) {
        int s   = wave * 256 + t * 64 + lane;
        int row = s >> 4;
        int lc  = (s & 15) ^ (row & 15);
        goffA[t] = row * RB + lc * 16;
    }
    const char* gA = (const char*)(eA + (size_t)jg * JBLK * RB);

    #pragma unroll
    for (int t = 0; t < 4; ++t)
        gload_lds16(gA + goffA[t], smem + wave * 4096 + t * 1024);

    const int ic0 = bi * BI + wave * 32 + col;   // this lane's i

    const int xm = col & 15;
    int poff[4];
    #pragma unroll
    for (int s = 0; s < 4; ++s)
        poff[s] = ((s * 4 + h * 2) ^ xm) << 4;   // partner chunk = poff[s]^16

    __syncthreads();   // drains A0 DMA

    float ts = 0.f;
    const int dpair = bi - jg * 4;   // sub-tile pair touching the diagonal (if 0..3)

    #pragma unroll
    for (int bjs = 0; bjs < NBJS; ++bjs) {
        if (bjs < NBJS - 1) {   // issue next A stage; drains at phase-end barrier
            const char* gAn = gA + (size_t)(bjs + 1) * JSUB * RB;
            #pragma unroll
            for (int t = 0; t < 4; ++t)
                gload_lds16(gAn + goffA[t],
                            smem + ((bjs + 1) & 1) * (JSUB * RB) + wave * 4096 + t * 1024);
        }

        const uint8_t* ab = smem + (bjs & 1) * (JSUB * RB);
        floatx16 acc[2];
        #pragma unroll
        for (int jt = 0; jt < 2; ++jt)
            acc[jt] = (floatx16){0.f,0.f,0.f,0.f,0.f,0.f,0.f,0.f,
                                 0.f,0.f,0.f,0.f,0.f,0.f,0.f,0.f};

        #pragma unroll
        for (int s = 0; s < 4; ++s) {
            int8v af[2];
            #pragma unroll
            for (int jt = 0; jt < 2; ++jt) {
                const uint8_t* pa = ab + (size_t)(jt * 32 + col) * RB;
                int4v lo = *(const int4v*)(pa + poff[s]);
                int4v hi = *(const int4v*)(pa + (poff[s] ^ 16));
                af[jt] = __builtin_shufflevector(lo, hi, 0, 1, 2, 3, 4, 5, 6, 7);
            }
            #pragma unroll
            for (int jt = 0; jt < 2; ++jt)
                acc[jt] = __builtin_amdgcn_mfma_scale_f32_32x32x64_f8f6f4(
                    af[jt], bfr[s], acc[jt], 0, 0,
                    0, SCALE_1_16, 0, SCALE_1_16);
        }

        const int jbs = jg * JBLK + bjs * JSUB;
        if ((bjs >> 1) == dpair)
            epi<true >(acc, jbs, h, ic0, ts);
        else
            epi<false>(acc, jbs, h, ic0, ts);

        if (bjs < NBJS - 1)
            __syncthreads();   // drains next-A DMA; guards restage of buffer just read
    }

    ts += __shfl_xor(ts, 32, 64);   // L and L+32: same i, disjoint j-halves
    if (h == 0)
        pts[(size_t)jg * NROWS + ic0] = ts;

    // ===== positives tail: 64 wave-slots per class (no LDS, no barriers) =====
    const int c   = bi;
    const int M   = ccnt[c];
    const int nbt = (M + 31) >> 5;
    const int w64 = jg * 4 + wave;
    const int bt  = w64 >> 3;
    const int at  = w64 & 7;
    if (bt >= nbt || at >= nbt) return;   // wave-divergent exit safe: no barriers below

    const int* idx = cidx + c * CAP;
    const int b    = bt * 32 + col;
    const int bidx = idx[min(b, M - 1)];

    const uint8_t* pb2 = eB + (size_t)bidx * RB + h * 32;
    int8v bpr[4];
    #pragma unroll
    for (int s = 0; s < 4; ++s)
        bpr[s] = *(const int8v*)(pb2 + s * 64);

    const uint8_t* pa2 = eA + (size_t)idx[min(at * 32 + col, M - 1)] * RB + h * 32;
    floatx16 acc2 = (floatx16){0.f,0.f,0.f,0.f,0.f,0.f,0.f,0.f,
                               0.f,0.f,0.f,0.f,0.f,0.f,0.f,0.f};
    #pragma unroll
    for (int s = 0; s < 4; ++s) {
        int8v af = *(const int8v*)(pa2 + s * 64);
        acc2 = __builtin_amdgcn_mfma_scale_f32_32x32x64_f8f6f4(
            af, bpr[s], acc2, 0, 0, 0, SCALE_1_16, 0, SCALE_1_16);
    }

    float psum = 0.f;
    #pragma unroll
    for (int rq = 0; rq < 4; ++rq)
        #pragma unroll
        for (int r2 = 0; r2 < 4; ++r2) {
            const int a = at * 32 + rq * 8 + h * 4 + r2;
            float v = EXP2(acc2[rq * 4 + r2]);
            psum += (a != b && a < M) ? v : 0.f;   // exact diag/pad mask
        }
    psum += __shfl_xor(psum, 32, 64);   // h-halves: disjoint a's, same b
    if (h == 0 && b < M)
        atomicAdd(&sp[bidx], psum);     // nbt contributors per row (one per a-tile)
}

// ---- Kernel 3: per-row log-diff + global sum ----
__global__ __launch_bounds__(256) void finalize_kernel(const float* __restrict__ pts,
                                                       const float* __restrict__ sp,
                                                       float* __restrict__ out)
{
    const int i = blockIdx.x * 256 + threadIdx.x;
    float st = 0.f;
    #pragma unroll
    for (int t = 0; t < NG; ++t)
        st += pts[(size_t)t * NROWS + i];
    const float spv = sp[i];
    const float ns  = st - spv;          // negatives = total - positives (diag-free both)
    float loss = logf(ns) - logf(spv);
    #pragma unroll
    for (int off = 32; off > 0; off >>= 1)
        loss += __shfl_xor(loss, off, 64);
    __shared__ float w4[4];
    if ((threadIdx.x & 63) == 0) w4[threadIdx.x >> 6] = loss;
    __syncthreads();
    if (threadIdx.x == 0)
        atomicAdd(out, w4[0] + w4[1] + w4[2] + w4[3]);
}

extern "C" void kernel_launch(void* const* d_in, const int* in_sizes, int n_in,
                              void* d_out, int out_size, void* d_ws, size_t ws_size,
                              hipStream_t stream)
{
    (void)in_sizes; (void)n_in; (void)out_size; (void)ws_size;
    const float* emb = (const float*)d_in[0];
    const int*   tgt = (const int*)d_in[1];
    float*       out = (float*)d_out;

    uint32_t* a8   = (uint32_t*)d_ws;                                 // 2 MB
    uint32_t* b8   = a8 + (size_t)NROWS * 64;                         // 2 MB
    float*    pts  = (float*)(b8 + (size_t)NROWS * 64);               // 512 KB
    float*    sp   = pts + (size_t)NG * NROWS;                        // 32 KB
    int*      cidx = (int*)(sp + NROWS);                              // 64 KB
    int*      ccnt = cidx + NCLS * CAP;                               // 256 B

    // merged: 2048 normalize blocks + 64 bucket blocks, one dispatch
    normalize_kernel<<<NROWS / 4 + NCLS, 256, 0, stream>>>(
        emb, tgt, a8, b8, cidx, ccnt, sp, out);

    dim3 grid(NIT, NG);   // exactly 1024 blocks = 4 per CU, no second round
    fused_kernel<<<grid, 256, 0, stream>>>(
        (const uint8_t*)a8, (const uint8_t*)b8, cidx, ccnt, pts, sp);

    finalize_kernel<<<NROWS / 256, 256, 0, stream>>>(pts, sp, out);
}